// Round 1
// baseline (3256.699 us; speedup 1.0000x reference)
//
#include <hip/hip_runtime.h>
#include <hip/hip_bf16.h>

// Problem constants (fixed by the reference setup_inputs)
constexpr int N_NODES = 50000;
constexpr int M_EDGES = 20000;
constexpr int E_INC   = 200000;
constexpr int D_DIM   = 128;
constexpr int H_HEADS = 8;
constexpr int HD      = 16;          // D / H
constexpr int C_CTX   = 64;
constexpr int NE_OUT  = 200000;
constexpr int R_REL   = 3 * N_NODES; // 150000
constexpr int FCHUNK  = 256;         // flash rows per block

__device__ __forceinline__ void fma4(float4& a, float s, const float4& w) {
    a.x += s * w.x; a.y += s * w.y; a.z += s * w.z; a.w += s * w.w;
}

// ---------------------------------------------------------------- zero fill
__global__ __launch_bounds__(256) void zero_kernel(float4* p, int n4) {
    int i = blockIdx.x * 256 + threadIdx.x;
    if (i < n4) p[i] = make_float4(0.f, 0.f, 0.f, 0.f);
}

// ------------------------------------------------- Y[r,:] = X[r,:]@W (+bias)
// X:[R,128], W:[128,128] row-major (k-major), Y:[R,128]. 32 rows/block.
__global__ __launch_bounds__(256) void gemm128_kernel(
    const float* __restrict__ X, const float* __restrict__ W,
    const float* __restrict__ bias, float* __restrict__ Y, int R)
{
    __shared__ float Wl[128 * 128];
    const float4* Wg4 = (const float4*)W;
    float4* Wl4 = (float4*)Wl;
#pragma unroll
    for (int i = 0; i < 16; ++i)
        Wl4[threadIdx.x + i * 256] = Wg4[threadIdx.x + i * 256];
    __syncthreads();

    const int cg = threadIdx.x & 31;   // column group: cols cg*4..cg*4+3
    const int rs = threadIdx.x >> 5;   // row slot 0..7
    const int rb = blockIdx.x * 32;

    float4 acc[4];
#pragma unroll
    for (int i = 0; i < 4; ++i) acc[i] = make_float4(0.f, 0.f, 0.f, 0.f);

    int rows[4];
#pragma unroll
    for (int i = 0; i < 4; ++i) {
        int r = rb + rs + 8 * i;
        rows[i] = (r < R) ? r : (R - 1);   // clamp; store is guarded
    }

    for (int k = 0; k < 128; k += 4) {
        float4 w0 = Wl4[(k + 0) * 32 + cg];
        float4 w1 = Wl4[(k + 1) * 32 + cg];
        float4 w2 = Wl4[(k + 2) * 32 + cg];
        float4 w3 = Wl4[(k + 3) * 32 + cg];
#pragma unroll
        for (int i = 0; i < 4; ++i) {
            float4 x4 = *(const float4*)(X + (size_t)rows[i] * 128 + k);
            fma4(acc[i], x4.x, w0);
            fma4(acc[i], x4.y, w1);
            fma4(acc[i], x4.z, w2);
            fma4(acc[i], x4.w, w3);
        }
    }

    float4 b4 = make_float4(0.f, 0.f, 0.f, 0.f);
    if (bias) b4 = ((const float4*)bias)[cg];
#pragma unroll
    for (int i = 0; i < 4; ++i) {
        int r = rb + rs + 8 * i;
        if (r < R) {
            float4 o = acc[i];
            o.x += b4.x; o.y += b4.y; o.z += b4.z; o.w += b4.w;
            ((float4*)Y)[(size_t)r * 32 + cg] = o;
        }
    }
}

// ----------------------------- dst[sidx[i],:] += src[gidx[i],:], deg[sidx]++
__global__ __launch_bounds__(256) void scatter_add_kernel(
    const float* __restrict__ src, const int* __restrict__ gidx,
    const int* __restrict__ sidx, float* __restrict__ dst,
    float* __restrict__ deg, int E)
{
    int t = blockIdx.x * 256 + threadIdx.x;
    int inc = t >> 5, lane = t & 31;
    if (inc >= E) return;
    int g = gidx[inc], s = sidx[inc];
    float4 a = ((const float4*)src)[(size_t)g * 32 + lane];
    float* dp = dst + (size_t)s * 128 + lane * 4;
    atomicAdd(dp + 0, a.x);
    atomicAdd(dp + 1, a.y);
    atomicAdd(dp + 2, a.z);
    atomicAdd(dp + 3, a.w);
    if (lane == 0) atomicAdd(deg + s, 1.0f);
}

// ------------------------------------------- buf[r,:] *= (deg[r]>0 ? 1/deg : 0)
__global__ __launch_bounds__(256) void scale_inv_deg_kernel(
    float* __restrict__ buf, const float* __restrict__ deg, int R)
{
    int t = blockIdx.x * 256 + threadIdx.x;
    int r = t >> 5, lane = t & 31;
    if (r >= R) return;
    float dg = deg[r];
    float s = dg > 0.f ? 1.f / dg : 0.f;
    float4* p = (float4*)buf + (size_t)r * 32 + lane;
    float4 v = *p;
    v.x *= s; v.y *= s; v.z *= s; v.w *= s;
    *p = v;
}

// ------------------------------- buf[r,:] = buf[r,:]*(1/deg) + bias[:]
__global__ __launch_bounds__(256) void scale_inv_deg_bias_kernel(
    float* __restrict__ buf, const float* __restrict__ deg,
    const float* __restrict__ bias, int R)
{
    int t = blockIdx.x * 256 + threadIdx.x;
    int r = t >> 5, lane = t & 31;
    if (r >= R) return;
    float dg = deg[r];
    float s = dg > 0.f ? 1.f / dg : 0.f;
    float4 b4 = ((const float4*)bias)[lane];
    float4* p = (float4*)buf + (size_t)r * 32 + lane;
    float4 v = *p;
    v.x = v.x * s + b4.x; v.y = v.y * s + b4.y;
    v.z = v.z * s + b4.z; v.w = v.w * s + b4.w;
    *p = v;
}

// --------------------------------------------------------- flash attention
// No max-subtraction (scores provably < ~1): partials are purely additive.
// grid = (NC, H). Block covers FCHUNK rows x 64 queries for one head.
// P[h][chunk][c][0] = sum_r exp(s), P[h][chunk][c][1+d] = sum_r exp(s)*v[r,d]
__global__ __launch_bounds__(256) void flash_kernel(
    const float* __restrict__ q,     // [64][128]
    const float* __restrict__ kbuf,  // [R][128]
    const float* __restrict__ vbuf,  // [R][128]
    float* __restrict__ P, int R, int NC)
{
    __shared__ float Kl[FCHUNK * 16];
    __shared__ float Vl[FCHUNK * 16];
    __shared__ float Pl[4 * 64 * 17];

    const int ch = blockIdx.x, h = blockIdx.y;
    const int base = ch * FCHUNK;
    const int rows = min(FCHUNK, R - base);

    // stage K/V chunk for this head (16 floats per row)
    for (int idx = threadIdx.x; idx < FCHUNK * 4; idx += 256) {
        int row = idx >> 2, c4 = idx & 3;
        if (row < rows) {
            ((float4*)Kl)[idx] = *(const float4*)(kbuf + (size_t)(base + row) * 128 + h * 16 + c4 * 4);
            ((float4*)Vl)[idx] = *(const float4*)(vbuf + (size_t)(base + row) * 128 + h * 16 + c4 * 4);
        }
    }

    const int c = threadIdx.x & 63;   // query index
    const int sl = threadIdx.x >> 6;  // row slice 0..3 (wave-uniform)
    float4 q4[4];
#pragma unroll
    for (int j = 0; j < 4; ++j)
        q4[j] = *(const float4*)(q + c * 128 + h * 16 + j * 4);
    __syncthreads();

    float l = 0.f;
    float4 o[4];
#pragma unroll
    for (int j = 0; j < 4; ++j) o[j] = make_float4(0.f, 0.f, 0.f, 0.f);

    for (int r = sl; r < rows; r += 4) {
        const float4* kr = (const float4*)(Kl + r * 16);
        float4 k0 = kr[0], k1 = kr[1], k2 = kr[2], k3 = kr[3];
        float s =
            q4[0].x * k0.x + q4[0].y * k0.y + q4[0].z * k0.z + q4[0].w * k0.w +
            q4[1].x * k1.x + q4[1].y * k1.y + q4[1].z * k1.z + q4[1].w * k1.w +
            q4[2].x * k2.x + q4[2].y * k2.y + q4[2].z * k2.z + q4[2].w * k2.w +
            q4[3].x * k3.x + q4[3].y * k3.y + q4[3].z * k3.z + q4[3].w * k3.w;
        float p = __expf(s * 0.25f);   // 1/sqrt(hd=16)
        l += p;
        const float4* vr = (const float4*)(Vl + r * 16);
        fma4(o[0], p, vr[0]);
        fma4(o[1], p, vr[1]);
        fma4(o[2], p, vr[2]);
        fma4(o[3], p, vr[3]);
    }

    // per-slice partials into LDS
    float* pp = Pl + (sl * 64 + c) * 17;
    pp[0] = l;
#pragma unroll
    for (int j = 0; j < 4; ++j) {
        pp[1 + j * 4 + 0] = o[j].x;
        pp[1 + j * 4 + 1] = o[j].y;
        pp[1 + j * 4 + 2] = o[j].z;
        pp[1 + j * 4 + 3] = o[j].w;
    }
    __syncthreads();

    // reduce 4 slices, write block partial (additive, no atomics)
    float* Pg = P + (size_t)(h * NC + ch) * 64 * 17;
    for (int item = threadIdx.x; item < 64 * 17; item += 256) {
        float v = Pl[item] + Pl[64 * 17 + item] + Pl[2 * 64 * 17 + item] + Pl[3 * 64 * 17 + item];
        Pg[item] = v;
    }
}

// --------------------------- combine partials -> osum[j] = sum_c o_norm[c,j]
__global__ __launch_bounds__(256) void combine_kernel(
    const float* __restrict__ P, float* __restrict__ osum, int NC)
{
    const int h = blockIdx.x;
    __shared__ float Ll[64];
    __shared__ float Ol[64 * 16];
    const float* Ph = P + (size_t)h * NC * 64 * 17;

    if (threadIdx.x < 64) {
        int c = threadIdx.x;
        float l = 0.f;
        for (int ch = 0; ch < NC; ++ch) l += Ph[(size_t)(ch * 64 + c) * 17];
        Ll[c] = l;
    }
    __syncthreads();

    for (int item = threadIdx.x; item < 1024; item += 256) {
        int c = item >> 4, d = item & 15;
        float s = 0.f;
        for (int ch = 0; ch < NC; ++ch) s += Ph[(size_t)(ch * 64 + c) * 17 + 1 + d];
        Ol[item] = s / Ll[c];
    }
    __syncthreads();

    if (threadIdx.x < 16) {
        int d = threadIdx.x;
        float s = 0.f;
        for (int c = 0; c < 64; ++c) s += Ol[c * 16 + d];
        osum[h * 16 + d] = s;
    }
}

// --- u[d] = (sum_c ctx[c,d] + (osum@wo)[d]/64 + bo[d]) / 65
__global__ __launch_bounds__(128) void user_kernel(
    const float* __restrict__ ctx, const float* __restrict__ osum,
    const float* __restrict__ wo, const float* __restrict__ bo,
    float* __restrict__ u)
{
    __shared__ float os[128];
    int d = threadIdx.x;
    os[d] = osum[d];
    __syncthreads();
    float cs = 0.f;
    for (int cc = 0; cc < 64; ++cc) cs += ctx[cc * 128 + d];
    float ow = 0.f;
    for (int j = 0; j < 128; ++j) ow += os[j] * wo[j * 128 + d];
    u[d] = (cs + ow * (1.f / 64.f) + bo[d]) * (1.f / 65.f);
}

// --------------------------------- out[j] = u @ w_rec[:,j] + b_rec[j]
__global__ __launch_bounds__(256) void rec_kernel(
    const float* __restrict__ u, const float* __restrict__ wrec,
    const float* __restrict__ brec, float* __restrict__ out)
{
    __shared__ float ul[128];
    if (threadIdx.x < 128) ul[threadIdx.x] = u[threadIdx.x];
    __syncthreads();
    int j = blockIdx.x * 256 + threadIdx.x;
    if (j >= NE_OUT) return;
    float a0 = brec[j], a1 = 0.f, a2 = 0.f, a3 = 0.f;
#pragma unroll 4
    for (int d = 0; d < 128; d += 4) {
        a0 += ul[d + 0] * wrec[(size_t)(d + 0) * NE_OUT + j];
        a1 += ul[d + 1] * wrec[(size_t)(d + 1) * NE_OUT + j];
        a2 += ul[d + 2] * wrec[(size_t)(d + 2) * NE_OUT + j];
        a3 += ul[d + 3] * wrec[(size_t)(d + 3) * NE_OUT + j];
    }
    out[j] = (a0 + a1) + (a2 + a3);
}

extern "C" void kernel_launch(void* const* d_in, const int* in_sizes, int n_in,
                              void* d_out, int out_size, void* d_ws, size_t ws_size,
                              hipStream_t stream)
{
    const float* x_item     = (const float*)d_in[0];
    const float* theta_item = (const float*)d_in[1];
    const float* bias_item  = (const float*)d_in[2];
    const float* x_ent      = (const float*)d_in[3];
    const float* theta_ent  = (const float*)d_in[4];
    const float* bias_ent   = (const float*)d_in[5];
    const float* x_word     = (const float*)d_in[6];
    const float* theta_word = (const float*)d_in[7];
    const float* bias_word  = (const float*)d_in[8];
    const float* ctx        = (const float*)d_in[9];
    const float* wq = (const float*)d_in[10];
    const float* bq = (const float*)d_in[11];
    const float* wk = (const float*)d_in[12];
    const float* bk = (const float*)d_in[13];
    const float* wv = (const float*)d_in[14];
    const float* bv = (const float*)d_in[15];
    const float* wo = (const float*)d_in[16];
    const float* bo = (const float*)d_in[17];
    const float* wrec = (const float*)d_in[18];
    const float* brec = (const float*)d_in[19];
    const int* node_item = (const int*)d_in[20];
    const int* edge_item = (const int*)d_in[21];
    const int* node_ent  = (const int*)d_in[22];
    const int* edge_ent  = (const int*)d_in[23];
    const int* node_word = (const int*)d_in[24];
    const int* edge_word = (const int*)d_in[25];
    float* out = (float*)d_out;

    // workspace layout
    char* ws = (char*)d_ws;
    size_t off = 0;
    auto alloc = [&](size_t nfloats) {
        float* p = (float*)(ws + off);
        off += nfloats * sizeof(float);
        return p;
    };
    const int NC = (R_REL + FCHUNK - 1) / FCHUNK;   // 586
    float* rel  = alloc((size_t)R_REL * 128);       // 76.8 MB (also concat target)
    float* xt   = alloc((size_t)N_NODES * 128);     // 25.6 MB (reused per modality)
    float* ebuf = alloc((size_t)M_EDGES * 128);     // 10.2 MB (reused)
    float* Bdeg = alloc(M_EDGES);                   // contiguous with ebuf for one zero-fill
    float* Dn   = alloc(N_NODES);
    float* kbuf = alloc((size_t)R_REL * 128);       // 76.8 MB
    float* vbuf = alloc((size_t)R_REL * 128);       // 76.8 MB
    float* qbuf = alloc(64 * 128);
    float* P    = alloc((size_t)H_HEADS * NC * 64 * 17);  // 20.4 MB
    float* osum = alloc(128);
    float* u    = alloc(128);
    (void)ws_size; (void)in_sizes; (void)n_in; (void)out_size;

    // zero rel (scatter target)
    {
        int n4 = R_REL * 128 / 4;
        zero_kernel<<<(n4 + 255) / 256, 256, 0, stream>>>((float4*)rel, n4);
    }

    const float* xs[3]  = {x_item, x_ent, x_word};
    const float* ths[3] = {theta_item, theta_ent, theta_word};
    const float* bs[3]  = {bias_item, bias_ent, bias_word};
    const int* nidx[3]  = {node_item, node_ent, node_word};
    const int* eidx[3]  = {edge_item, edge_ent, edge_word};

    for (int m = 0; m < 3; ++m) {
        // xt = x @ theta
        gemm128_kernel<<<(N_NODES + 31) / 32, 256, 0, stream>>>(xs[m], ths[m], nullptr, xt, N_NODES);
        // zero ebuf + Bdeg + Dn (contiguous region)
        int n4 = (M_EDGES * 128 + M_EDGES + N_NODES) / 4;
        zero_kernel<<<(n4 + 255) / 256, 256, 0, stream>>>((float4*)ebuf, n4);
        // e[edge] += xt[node]; B[edge] += 1
        scatter_add_kernel<<<E_INC * 32 / 256, 256, 0, stream>>>(xt, nidx[m], eidx[m], ebuf, Bdeg, E_INC);
        // e *= Binv
        scale_inv_deg_kernel<<<M_EDGES * 32 / 256, 256, 0, stream>>>(ebuf, Bdeg, M_EDGES);
        // out[node] += e[edge]; Dn[node] += 1
        float* relm = rel + (size_t)m * N_NODES * 128;
        scatter_add_kernel<<<E_INC * 32 / 256, 256, 0, stream>>>(ebuf, eidx[m], nidx[m], relm, Dn, E_INC);
        // out = out*Dinv + bias
        scale_inv_deg_bias_kernel<<<N_NODES * 32 / 256, 256, 0, stream>>>(relm, Dn, bs[m], N_NODES);
    }

    // q / k / v projections
    gemm128_kernel<<<2, 256, 0, stream>>>(ctx, wq, bq, qbuf, C_CTX);
    gemm128_kernel<<<(R_REL + 31) / 32, 256, 0, stream>>>(rel, wk, bk, kbuf, R_REL);
    gemm128_kernel<<<(R_REL + 31) / 32, 256, 0, stream>>>(rel, wv, bv, vbuf, R_REL);

    // streaming attention partials + combine
    flash_kernel<<<dim3(NC, H_HEADS), 256, 0, stream>>>(qbuf, kbuf, vbuf, P, R_REL, NC);
    combine_kernel<<<H_HEADS, 256, 0, stream>>>(P, osum, NC);

    // pooled user representation
    user_kernel<<<1, 128, 0, stream>>>(ctx, osum, wo, bo, u);

    // final scores
    rec_kernel<<<(NE_OUT + 255) / 256, 256, 0, stream>>>(u, wrec, brec, out);
}

// Round 2
// 1031.612 us; speedup vs baseline: 3.1569x; 3.1569x over previous
//
#include <hip/hip_runtime.h>
#include <hip/hip_bf16.h>

// Problem constants (fixed by the reference setup_inputs)
constexpr int N_NODES = 50000;
constexpr int M_EDGES = 20000;
constexpr int E_INC   = 200000;
constexpr int H_HEADS = 8;
constexpr int C_CTX   = 64;
constexpr int NE_OUT  = 200000;
constexpr int R_REL   = 3 * N_NODES; // 150000
constexpr int FCHUNK  = 256;         // flash rows per block

__device__ __forceinline__ void fma4(float4& a, float s, const float4& w) {
    a.x += s * w.x; a.y += s * w.y; a.z += s * w.z; a.w += s * w.w;
}

// ---------------------------------------------------------------- zero fill
__global__ __launch_bounds__(256) void zero_kernel(float4* p, int n4) {
    int i = blockIdx.x * 256 + threadIdx.x;
    if (i < n4) p[i] = make_float4(0.f, 0.f, 0.f, 0.f);
}

// ------------------------------------------------- Y[r,:] = X[r,:]@W (+bias)
__global__ __launch_bounds__(256) void gemm128_kernel(
    const float* __restrict__ X, const float* __restrict__ W,
    const float* __restrict__ bias, float* __restrict__ Y, int R)
{
    __shared__ float Wl[128 * 128];
    const float4* Wg4 = (const float4*)W;
    float4* Wl4 = (float4*)Wl;
#pragma unroll
    for (int i = 0; i < 16; ++i)
        Wl4[threadIdx.x + i * 256] = Wg4[threadIdx.x + i * 256];
    __syncthreads();

    const int cg = threadIdx.x & 31;
    const int rs = threadIdx.x >> 5;
    const int rb = blockIdx.x * 32;

    float4 acc[4];
#pragma unroll
    for (int i = 0; i < 4; ++i) acc[i] = make_float4(0.f, 0.f, 0.f, 0.f);

    int rows[4];
#pragma unroll
    for (int i = 0; i < 4; ++i) {
        int r = rb + rs + 8 * i;
        rows[i] = (r < R) ? r : (R - 1);
    }

    for (int k = 0; k < 128; k += 4) {
        float4 w0 = Wl4[(k + 0) * 32 + cg];
        float4 w1 = Wl4[(k + 1) * 32 + cg];
        float4 w2 = Wl4[(k + 2) * 32 + cg];
        float4 w3 = Wl4[(k + 3) * 32 + cg];
#pragma unroll
        for (int i = 0; i < 4; ++i) {
            float4 x4 = *(const float4*)(X + (size_t)rows[i] * 128 + k);
            fma4(acc[i], x4.x, w0);
            fma4(acc[i], x4.y, w1);
            fma4(acc[i], x4.z, w2);
            fma4(acc[i], x4.w, w3);
        }
    }

    float4 b4 = make_float4(0.f, 0.f, 0.f, 0.f);
    if (bias) b4 = ((const float4*)bias)[cg];
#pragma unroll
    for (int i = 0; i < 4; ++i) {
        int r = rb + rs + 8 * i;
        if (r < R) {
            float4 o = acc[i];
            o.x += b4.x; o.y += b4.y; o.z += b4.z; o.w += b4.w;
            ((float4*)Y)[(size_t)r * 32 + cg] = o;
        }
    }
}

// --------------------------------------------------- CSR build: count
__global__ __launch_bounds__(256) void count_kernel(
    const int* __restrict__ idx, int* __restrict__ cnt, int E)
{
    int i = blockIdx.x * 256 + threadIdx.x;
    if (i < E) atomicAdd(&cnt[idx[i]], 1);
}

// --------------------------------------------------- CSR build: 6-way scan
// cnts: [3x20000][3x50000] contiguous; offs: [3x20001][3x50001] contiguous.
__global__ __launch_bounds__(256) void scan6_kernel(
    const int* __restrict__ cnts, int* __restrict__ offs)
{
    const int lens[6] = {M_EDGES, M_EDGES, M_EDGES, N_NODES, N_NODES, N_NODES};
    int b = blockIdx.x;
    int cbase = 0, obase = 0;
    for (int i = 0; i < b; ++i) { cbase += lens[i]; obase += lens[i] + 1; }
    const int* cnt = cnts + cbase;
    int* off = offs + obase;
    const int len = lens[b];

    const int t = threadIdx.x, lane = t & 63, w = t >> 6;
    __shared__ int wsum[2][4];
    int carry = 0;
    int buf = 0;
    for (int base = 0; base < len; base += 1024, buf ^= 1) {
        int i0 = base + t * 4;
        int v0 = (i0 + 0 < len) ? cnt[i0 + 0] : 0;
        int v1 = (i0 + 1 < len) ? cnt[i0 + 1] : 0;
        int v2 = (i0 + 2 < len) ? cnt[i0 + 2] : 0;
        int v3 = (i0 + 3 < len) ? cnt[i0 + 3] : 0;
        int s = v0 + v1 + v2 + v3;
        int incl = s;
#pragma unroll
        for (int d = 1; d < 64; d <<= 1) {
            int x = __shfl_up(incl, d, 64);
            if (lane >= d) incl += x;
        }
        if (lane == 63) wsum[buf][w] = incl;
        __syncthreads();
        int prefix = carry;
        for (int ww = 0; ww < w; ++ww) prefix += wsum[buf][ww];
        int excl = prefix + incl - s;
        if (i0 + 0 < len) off[i0 + 0] = excl;
        if (i0 + 1 < len) off[i0 + 1] = excl + v0;
        if (i0 + 2 < len) off[i0 + 2] = excl + v0 + v1;
        if (i0 + 3 < len) off[i0 + 3] = excl + v0 + v1 + v2;
        carry += wsum[buf][0] + wsum[buf][1] + wsum[buf][2] + wsum[buf][3];
    }
    if (t == 0) off[len] = carry;
}

// --------------------------------------------------- CSR build: fill
// Uses cnt as a countdown cursor (ends at 0; deg recovered from offsets).
__global__ __launch_bounds__(256) void fill_kernel(
    const int* __restrict__ idx, const int* __restrict__ other,
    const int* __restrict__ off, int* __restrict__ cnt,
    int* __restrict__ list, int E)
{
    int i = blockIdx.x * 256 + threadIdx.x;
    if (i >= E) return;
    int e = idx[i];
    int pos = atomicSub(&cnt[e], 1) - 1;
    list[off[e] + pos] = other[i];
}

// ------------------- ebuf[e,:] = (sum_{n in list(e)} xt[n,:]) / deg(e)
__global__ __launch_bounds__(256) void gather_edge_kernel(
    const float* __restrict__ xt, const int* __restrict__ list,
    const int* __restrict__ off, float* __restrict__ ebuf, int M)
{
    int t = blockIdx.x * 256 + threadIdx.x;
    int e = t >> 5, lane = t & 31;
    if (e >= M) return;
    int s = off[e], en = off[e + 1];
    float4 acc = make_float4(0.f, 0.f, 0.f, 0.f);
    for (int j = s; j < en; ++j) {
        int n = list[j];
        float4 v = ((const float4*)xt)[(size_t)n * 32 + lane];
        acc.x += v.x; acc.y += v.y; acc.z += v.z; acc.w += v.w;
    }
    float binv = (en > s) ? 1.f / (float)(en - s) : 0.f;
    ((float4*)ebuf)[(size_t)e * 32 + lane] =
        make_float4(acc.x * binv, acc.y * binv, acc.z * binv, acc.w * binv);
}

// ----- rel[n,:] = (sum_{e in list(n)} ebuf[e,:]) / deg(n) + bias[:]
__global__ __launch_bounds__(256) void gather_node_kernel(
    const float* __restrict__ ebuf, const int* __restrict__ list,
    const int* __restrict__ off, const float* __restrict__ bias,
    float* __restrict__ rel, int N)
{
    int t = blockIdx.x * 256 + threadIdx.x;
    int n = t >> 5, lane = t & 31;
    if (n >= N) return;
    int s = off[n], en = off[n + 1];
    float4 acc = make_float4(0.f, 0.f, 0.f, 0.f);
    for (int j = s; j < en; ++j) {
        int e = list[j];
        float4 v = ((const float4*)ebuf)[(size_t)e * 32 + lane];
        acc.x += v.x; acc.y += v.y; acc.z += v.z; acc.w += v.w;
    }
    float dinv = (en > s) ? 1.f / (float)(en - s) : 0.f;
    float4 b4 = ((const float4*)bias)[lane];
    ((float4*)rel)[(size_t)n * 32 + lane] =
        make_float4(acc.x * dinv + b4.x, acc.y * dinv + b4.y,
                    acc.z * dinv + b4.z, acc.w * dinv + b4.w);
}

// --------------------------------------------------------- flash attention
// No max-subtraction (scores provably < ~1): partials are purely additive.
__global__ __launch_bounds__(256) void flash_kernel(
    const float* __restrict__ q,     // [64][128]
    const float* __restrict__ kbuf,  // [R][128]
    const float* __restrict__ vbuf,  // [R][128]
    float* __restrict__ P, int R, int NC)
{
    __shared__ float Kl[FCHUNK * 16];
    __shared__ float Vl[FCHUNK * 16];
    __shared__ float Pl[4 * 64 * 17];

    const int ch = blockIdx.x, h = blockIdx.y;
    const int base = ch * FCHUNK;
    const int rows = min(FCHUNK, R - base);

    for (int idx = threadIdx.x; idx < FCHUNK * 4; idx += 256) {
        int row = idx >> 2, c4 = idx & 3;
        if (row < rows) {
            ((float4*)Kl)[idx] = *(const float4*)(kbuf + (size_t)(base + row) * 128 + h * 16 + c4 * 4);
            ((float4*)Vl)[idx] = *(const float4*)(vbuf + (size_t)(base + row) * 128 + h * 16 + c4 * 4);
        }
    }

    const int c = threadIdx.x & 63;
    const int sl = threadIdx.x >> 6;
    float4 q4[4];
#pragma unroll
    for (int j = 0; j < 4; ++j)
        q4[j] = *(const float4*)(q + c * 128 + h * 16 + j * 4);
    __syncthreads();

    float l = 0.f;
    float4 o[4];
#pragma unroll
    for (int j = 0; j < 4; ++j) o[j] = make_float4(0.f, 0.f, 0.f, 0.f);

    for (int r = sl; r < rows; r += 4) {
        const float4* kr = (const float4*)(Kl + r * 16);
        float4 k0 = kr[0], k1 = kr[1], k2 = kr[2], k3 = kr[3];
        float s =
            q4[0].x * k0.x + q4[0].y * k0.y + q4[0].z * k0.z + q4[0].w * k0.w +
            q4[1].x * k1.x + q4[1].y * k1.y + q4[1].z * k1.z + q4[1].w * k1.w +
            q4[2].x * k2.x + q4[2].y * k2.y + q4[2].z * k2.z + q4[2].w * k2.w +
            q4[3].x * k3.x + q4[3].y * k3.y + q4[3].z * k3.z + q4[3].w * k3.w;
        float p = __expf(s * 0.25f);
        l += p;
        const float4* vr = (const float4*)(Vl + r * 16);
        fma4(o[0], p, vr[0]);
        fma4(o[1], p, vr[1]);
        fma4(o[2], p, vr[2]);
        fma4(o[3], p, vr[3]);
    }

    float* pp = Pl + (sl * 64 + c) * 17;
    pp[0] = l;
#pragma unroll
    for (int j = 0; j < 4; ++j) {
        pp[1 + j * 4 + 0] = o[j].x;
        pp[1 + j * 4 + 1] = o[j].y;
        pp[1 + j * 4 + 2] = o[j].z;
        pp[1 + j * 4 + 3] = o[j].w;
    }
    __syncthreads();

    float* Pg = P + (size_t)(h * NC + ch) * 64 * 17;
    for (int item = threadIdx.x; item < 64 * 17; item += 256) {
        float v = Pl[item] + Pl[64 * 17 + item] + Pl[2 * 64 * 17 + item] + Pl[3 * 64 * 17 + item];
        Pg[item] = v;
    }
}

// ------------------- combine stage 1: one block per (h,c); Onorm[h][c][16]
__global__ __launch_bounds__(256) void combine1_kernel(
    const float* __restrict__ P, float* __restrict__ Onorm, int NC)
{
    const int h = blockIdx.x >> 6, c = blockIdx.x & 63;
    const int t = threadIdx.x;
    const int comp = t & 31, grp = t >> 5;
    __shared__ float red[8][32];

    float acc = 0.f;
    if (comp < 17) {
        for (int ch = grp; ch < NC; ch += 8)
            acc += P[((size_t)(h * NC + ch) * 64 + c) * 17 + comp];
    }
    red[grp][comp] = acc;
    __syncthreads();
    if (t < 32) {
        float s = red[0][t] + red[1][t] + red[2][t] + red[3][t]
                + red[4][t] + red[5][t] + red[6][t] + red[7][t];
        red[0][t] = s;
    }
    __syncthreads();
    if (t >= 1 && t < 17) {
        float l = red[0][0];
        Onorm[(size_t)(h * 64 + c) * 16 + (t - 1)] = red[0][t] / l;
    }
}

// ------------------- combine stage 2: osum[h*16+d] = sum_c Onorm[h][c][d]
__global__ __launch_bounds__(128) void combine2_kernel(
    const float* __restrict__ Onorm, float* __restrict__ osum)
{
    int t = threadIdx.x;           // t = h*16 + d
    int h = t >> 4, d = t & 15;
    float s = 0.f;
    for (int c = 0; c < 64; ++c)
        s += Onorm[(size_t)(h * 64 + c) * 16 + d];
    osum[t] = s;
}

// --- u[d] = (sum_c ctx[c,d] + (osum@wo)[d]/64 + bo[d]) / 65
__global__ __launch_bounds__(128) void user_kernel(
    const float* __restrict__ ctx, const float* __restrict__ osum,
    const float* __restrict__ wo, const float* __restrict__ bo,
    float* __restrict__ u)
{
    __shared__ float os[128];
    int d = threadIdx.x;
    os[d] = osum[d];
    __syncthreads();
    float cs = 0.f;
    for (int cc = 0; cc < 64; ++cc) cs += ctx[cc * 128 + d];
    float ow = 0.f;
    for (int j = 0; j < 128; ++j) ow += os[j] * wo[j * 128 + d];
    u[d] = (cs + ow * (1.f / 64.f) + bo[d]) * (1.f / 65.f);
}

// --------------------------------- out[j] = u @ w_rec[:,j] + b_rec[j]
__global__ __launch_bounds__(256) void rec_kernel(
    const float* __restrict__ u, const float* __restrict__ wrec,
    const float* __restrict__ brec, float* __restrict__ out)
{
    __shared__ float ul[128];
    if (threadIdx.x < 128) ul[threadIdx.x] = u[threadIdx.x];
    __syncthreads();
    int j = blockIdx.x * 256 + threadIdx.x;
    if (j >= NE_OUT) return;
    float a0 = brec[j], a1 = 0.f, a2 = 0.f, a3 = 0.f;
#pragma unroll 4
    for (int d = 0; d < 128; d += 4) {
        a0 += ul[d + 0] * wrec[(size_t)(d + 0) * NE_OUT + j];
        a1 += ul[d + 1] * wrec[(size_t)(d + 1) * NE_OUT + j];
        a2 += ul[d + 2] * wrec[(size_t)(d + 2) * NE_OUT + j];
        a3 += ul[d + 3] * wrec[(size_t)(d + 3) * NE_OUT + j];
    }
    out[j] = (a0 + a1) + (a2 + a3);
}

extern "C" void kernel_launch(void* const* d_in, const int* in_sizes, int n_in,
                              void* d_out, int out_size, void* d_ws, size_t ws_size,
                              hipStream_t stream)
{
    const float* x_item     = (const float*)d_in[0];
    const float* theta_item = (const float*)d_in[1];
    const float* bias_item  = (const float*)d_in[2];
    const float* x_ent      = (const float*)d_in[3];
    const float* theta_ent  = (const float*)d_in[4];
    const float* bias_ent   = (const float*)d_in[5];
    const float* x_word     = (const float*)d_in[6];
    const float* theta_word = (const float*)d_in[7];
    const float* bias_word  = (const float*)d_in[8];
    const float* ctx        = (const float*)d_in[9];
    const float* wq = (const float*)d_in[10];
    const float* bq = (const float*)d_in[11];
    const float* wk = (const float*)d_in[12];
    const float* bk = (const float*)d_in[13];
    const float* wv = (const float*)d_in[14];
    const float* bv = (const float*)d_in[15];
    const float* wo = (const float*)d_in[16];
    const float* bo = (const float*)d_in[17];
    const float* wrec = (const float*)d_in[18];
    const float* brec = (const float*)d_in[19];
    const int* node_idx[3] = {(const int*)d_in[20], (const int*)d_in[22], (const int*)d_in[24]};
    const int* edge_idx[3] = {(const int*)d_in[21], (const int*)d_in[23], (const int*)d_in[25]};
    float* out = (float*)d_out;

    // workspace layout
    char* ws = (char*)d_ws;
    size_t off = 0;
    auto alloc = [&](size_t nfloats) {
        float* p = (float*)(ws + off);
        off += nfloats * sizeof(float);
        return p;
    };
    const int NC = (R_REL + FCHUNK - 1) / FCHUNK;   // 586
    float* rel   = alloc((size_t)R_REL * 128);
    float* xt    = alloc((size_t)N_NODES * 128);
    float* ebuf  = alloc((size_t)M_EDGES * 128);
    float* kbuf  = alloc((size_t)R_REL * 128);
    float* vbuf  = alloc((size_t)R_REL * 128);
    float* qbuf  = alloc(64 * 128);
    float* P     = alloc((size_t)H_HEADS * NC * 64 * 17);  // 20.4 MB
    float* Onorm = alloc(H_HEADS * 64 * 16);
    float* osum  = alloc(128);
    float* u     = alloc(128);
    (void)ws_size; (void)in_sizes; (void)n_in; (void)out_size;

    // ---- CSR scratch aliases P (P only written later by flash_kernel) ----
    // cnt: 3x20000 (edges) then 3x50000 (nodes)   = 210000 ints
    // off: 3x20001 then 3x50001                   = 210006 ints
    // lists: 3xE (edge-grouped node lists), 3xE (node-grouped edge lists)
    int* cntbase  = (int*)P;
    int* offbase  = cntbase + 3 * M_EDGES + 3 * N_NODES;
    int* listbase = offbase + 3 * (M_EDGES + 1) + 3 * (N_NODES + 1);
    int* ecnt[3], *ncnt[3], *eoff[3], *noff[3], *elist[3], *nlist[3];
    for (int m = 0; m < 3; ++m) {
        ecnt[m] = cntbase + m * M_EDGES;
        ncnt[m] = cntbase + 3 * M_EDGES + m * N_NODES;
        eoff[m] = offbase + m * (M_EDGES + 1);
        noff[m] = offbase + 3 * (M_EDGES + 1) + m * (N_NODES + 1);
        elist[m] = listbase + m * E_INC;
        nlist[m] = listbase + 3 * E_INC + m * E_INC;
    }

    // ---- build CSR (both directions, all modalities) ----
    {
        int nints = 3 * M_EDGES + 3 * N_NODES;        // 210000, divisible by 4
        zero_kernel<<<(nints / 4 + 255) / 256, 256, 0, stream>>>((float4*)cntbase, nints / 4);
    }
    const int gE = (E_INC + 255) / 256;
    for (int m = 0; m < 3; ++m) {
        count_kernel<<<gE, 256, 0, stream>>>(edge_idx[m], ecnt[m], E_INC);
        count_kernel<<<gE, 256, 0, stream>>>(node_idx[m], ncnt[m], E_INC);
    }
    scan6_kernel<<<6, 256, 0, stream>>>(cntbase, offbase);
    for (int m = 0; m < 3; ++m) {
        fill_kernel<<<gE, 256, 0, stream>>>(edge_idx[m], node_idx[m], eoff[m], ecnt[m], elist[m], E_INC);
        fill_kernel<<<gE, 256, 0, stream>>>(node_idx[m], edge_idx[m], noff[m], ncnt[m], nlist[m], E_INC);
    }

    // ---- hypergraph conv per modality ----
    const float* xs[3]  = {x_item, x_ent, x_word};
    const float* ths[3] = {theta_item, theta_ent, theta_word};
    const float* bs[3]  = {bias_item, bias_ent, bias_word};
    for (int m = 0; m < 3; ++m) {
        gemm128_kernel<<<(N_NODES + 31) / 32, 256, 0, stream>>>(xs[m], ths[m], nullptr, xt, N_NODES);
        gather_edge_kernel<<<(M_EDGES * 32) / 256, 256, 0, stream>>>(xt, elist[m], eoff[m], ebuf, M_EDGES);
        float* relm = rel + (size_t)m * N_NODES * 128;
        gather_node_kernel<<<(N_NODES * 32) / 256, 256, 0, stream>>>(ebuf, nlist[m], noff[m], bs[m], relm, N_NODES);
    }

    // ---- q / k / v projections ----
    gemm128_kernel<<<2, 256, 0, stream>>>(ctx, wq, bq, qbuf, C_CTX);
    gemm128_kernel<<<(R_REL + 31) / 32, 256, 0, stream>>>(rel, wk, bk, kbuf, R_REL);
    gemm128_kernel<<<(R_REL + 31) / 32, 256, 0, stream>>>(rel, wv, bv, vbuf, R_REL);

    // ---- streaming attention + combine ----
    flash_kernel<<<dim3(NC, H_HEADS), 256, 0, stream>>>(qbuf, kbuf, vbuf, P, R_REL, NC);
    combine1_kernel<<<H_HEADS * 64, 256, 0, stream>>>(P, Onorm, NC);
    combine2_kernel<<<1, 128, 0, stream>>>(Onorm, osum);

    // ---- pooled user representation + final scores ----
    user_kernel<<<1, 128, 0, stream>>>(ctx, osum, wo, bo, u);
    rec_kernel<<<(NE_OUT + 255) / 256, 256, 0, stream>>>(u, wrec, brec, out);
}

// Round 3
// 679.795 us; speedup vs baseline: 4.7907x; 1.5175x over previous
//
#include <hip/hip_runtime.h>
#include <hip/hip_bf16.h>

// Problem constants (fixed by the reference setup_inputs)
constexpr int N_NODES = 50000;
constexpr int M_EDGES = 20000;
constexpr int E_INC   = 200000;
constexpr int H_HEADS = 8;
constexpr int C_CTX   = 64;
constexpr int NE_OUT  = 200000;
constexpr int R_REL   = 3 * N_NODES; // 150000

constexpr int STRIPS  = 128;
constexpr int SROWS   = 1172;        // ceil(150000/128)
constexpr int SCHUNKS = 19;          // ceil(1172/64)

typedef short bf8v __attribute__((ext_vector_type(8)));   // 8 bf16 (4 VGPRs)
typedef float f4v  __attribute__((ext_vector_type(4)));   // 4 fp32 acc
#define MFMA16(a, b, c) __builtin_amdgcn_mfma_f32_16x16x32_bf16(a, b, c, 0, 0, 0)

__device__ __forceinline__ unsigned bfb(float f) {   // fp32 -> bf16 bits (RNE)
    union { float f; unsigned u; } v; v.f = f;
    return (v.u + 0x7FFFu + ((v.u >> 16) & 1u)) >> 16;
}

// ---------------------------------------------------------------- zero fill
__global__ __launch_bounds__(256) void zero_kernel(float4* p, int n4) {
    int i = blockIdx.x * 256 + threadIdx.x;
    if (i < n4) p[i] = make_float4(0.f, 0.f, 0.f, 0.f);
}

// --------------------------- old fp32 GEMM, kept only for qbuf (64 rows)
__global__ __launch_bounds__(256) void gemm128_kernel(
    const float* __restrict__ X, const float* __restrict__ W,
    const float* __restrict__ bias, float* __restrict__ Y, int R)
{
    __shared__ float Wl[128 * 128];
    const float4* Wg4 = (const float4*)W;
    float4* Wl4 = (float4*)Wl;
#pragma unroll
    for (int i = 0; i < 16; ++i)
        Wl4[threadIdx.x + i * 256] = Wg4[threadIdx.x + i * 256];
    __syncthreads();
    const int cg = threadIdx.x & 31, rs = threadIdx.x >> 5, rb = blockIdx.x * 32;
    float4 acc[4];
#pragma unroll
    for (int i = 0; i < 4; ++i) acc[i] = make_float4(0.f, 0.f, 0.f, 0.f);
    int rows[4];
#pragma unroll
    for (int i = 0; i < 4; ++i) {
        int r = rb + rs + 8 * i;
        rows[i] = (r < R) ? r : (R - 1);
    }
    for (int k = 0; k < 128; k += 4) {
        float4 w0 = Wl4[(k + 0) * 32 + cg];
        float4 w1 = Wl4[(k + 1) * 32 + cg];
        float4 w2 = Wl4[(k + 2) * 32 + cg];
        float4 w3 = Wl4[(k + 3) * 32 + cg];
#pragma unroll
        for (int i = 0; i < 4; ++i) {
            float4 x4 = *(const float4*)(X + (size_t)rows[i] * 128 + k);
            acc[i].x += x4.x * w0.x + x4.y * w1.x + x4.z * w2.x + x4.w * w3.x;
            acc[i].y += x4.x * w0.y + x4.y * w1.y + x4.z * w2.y + x4.w * w3.y;
            acc[i].z += x4.x * w0.z + x4.y * w1.z + x4.z * w2.z + x4.w * w3.z;
            acc[i].w += x4.x * w0.w + x4.y * w1.w + x4.z * w2.w + x4.w * w3.w;
        }
    }
    float4 b4 = ((const float4*)bias)[cg];
#pragma unroll
    for (int i = 0; i < 4; ++i) {
        int r = rb + rs + 8 * i;
        if (r < R) {
            float4 o = acc[i];
            o.x += b4.x; o.y += b4.y; o.z += b4.z; o.w += b4.w;
            ((float4*)Y)[(size_t)r * 32 + cg] = o;
        }
    }
}

// ------------------------------------------- theta -> bf16 transposed [n][k]
__global__ __launch_bounds__(256) void wconv_kernel(
    const float* __restrict__ t0, const float* __restrict__ t1,
    const float* __restrict__ t2, unsigned short* __restrict__ out)
{
    int idx = blockIdx.x * 256 + threadIdx.x;   // 0..49151
    int m = idx >> 14, p = idx & 16383;
    int n = p >> 7, k = p & 127;
    const float* src = (m == 0) ? t0 : (m == 1) ? t1 : t2;
    out[idx] = (unsigned short)bfb(src[k * 128 + n]);
}

// --------- qk[hc][j] = 0.25 * sum_d q[c,h16+d]*wk[j,h16+d];  cb likewise
__global__ __launch_bounds__(256) void qk_kernel(
    const float* __restrict__ qbuf, const float* __restrict__ wk,
    const float* __restrict__ bk, unsigned short* __restrict__ qkb,
    float* __restrict__ cb)
{
    int idx = blockIdx.x * 256 + threadIdx.x;   // 65536
    int hc = idx >> 7, j = idx & 127;
    int h = hc >> 6, c = hc & 63;
    const float* qr = qbuf + c * 128 + h * 16;
    const float* wr = wk + (size_t)j * 128 + h * 16;
    float s = 0.f;
#pragma unroll
    for (int d = 0; d < 16; ++d) s += qr[d] * wr[d];
    qkb[idx] = (unsigned short)bfb(0.25f * s);
    if (j == 0) {
        float t = 0.f;
#pragma unroll
        for (int d = 0; d < 16; ++d) t += qr[d] * bk[h * 16 + d];
        cb[hc] = 0.25f * t;
    }
}

// ------------------- xt(bf16) = x(fp32) @ theta  via MFMA, grid (391, 3)
__global__ __launch_bounds__(256) void xg_kernel(
    const float* __restrict__ x0, const float* __restrict__ x1,
    const float* __restrict__ x2, const unsigned short* __restrict__ thT,
    unsigned short* __restrict__ y, int R)
{
    int m = blockIdx.y;
    const float* X = (m == 0) ? x0 : (m == 1) ? x1 : x2;
    const unsigned short* W = thT + m * 16384;
    unsigned short* Y = y + (size_t)m * R * 128;
    const int w = threadIdx.x >> 6, lane = threadIdx.x & 63;
    const int ln15 = lane & 15, l16 = lane >> 4;
    const int r0 = blockIdx.x * 128 + w * 32;

    f4v acc[2][8];
#pragma unroll
    for (int i = 0; i < 2; ++i)
#pragma unroll
        for (int j = 0; j < 8; ++j) acc[i][j] = (f4v)0.f;

    for (int ks = 0; ks < 4; ++ks) {
        bf8v a[2];
#pragma unroll
        for (int mt = 0; mt < 2; ++mt) {
            int row = r0 + mt * 16 + ln15;
            row = (row < R) ? row : (R - 1);
            const float* xp = X + (size_t)row * 128 + ks * 32 + l16 * 8;
            float4 f0 = *(const float4*)xp;
            float4 f1 = *(const float4*)(xp + 4);
            union { bf8v v; unsigned w[4]; } u;
            u.w[0] = bfb(f0.x) | (bfb(f0.y) << 16);
            u.w[1] = bfb(f0.z) | (bfb(f0.w) << 16);
            u.w[2] = bfb(f1.x) | (bfb(f1.y) << 16);
            u.w[3] = bfb(f1.z) | (bfb(f1.w) << 16);
            a[mt] = u.v;
        }
#pragma unroll
        for (int nt = 0; nt < 8; ++nt) {
            bf8v b = *(const bf8v*)(W + (nt * 16 + ln15) * 128 + ks * 32 + l16 * 8);
            acc[0][nt] = MFMA16(a[0], b, acc[0][nt]);
            acc[1][nt] = MFMA16(a[1], b, acc[1][nt]);
        }
    }
#pragma unroll
    for (int mt = 0; mt < 2; ++mt)
#pragma unroll
        for (int reg = 0; reg < 4; ++reg) {
            int row = r0 + mt * 16 + l16 * 4 + reg;
            if (row < R) {
#pragma unroll
                for (int nt = 0; nt < 8; ++nt)
                    Y[(size_t)row * 128 + nt * 16 + ln15] = (unsigned short)bfb(acc[mt][nt][reg]);
            }
        }
}

// --------------------------------------------------- CSR build: count (x6)
__global__ __launch_bounds__(256) void count6_kernel(
    const int* e0, const int* e1, const int* e2,
    const int* n0, const int* n1, const int* n2, int* cntbase)
{
    int b = blockIdx.y;
    const int* arr = (b == 0) ? e0 : (b == 1) ? e1 : (b == 2) ? e2
                   : (b == 3) ? n0 : (b == 4) ? n1 : n2;
    int base = (b < 3) ? b * M_EDGES : 3 * M_EDGES + (b - 3) * N_NODES;
    int i = blockIdx.x * 256 + threadIdx.x;
    if (i < E_INC) atomicAdd(cntbase + base + arr[i], 1);
}

// --------------------------------------------------- CSR build: 6-way scan
__global__ __launch_bounds__(256) void scan6_kernel(
    const int* __restrict__ cnts, int* __restrict__ offs)
{
    const int lens[6] = {M_EDGES, M_EDGES, M_EDGES, N_NODES, N_NODES, N_NODES};
    int b = blockIdx.x;
    int cbase = 0, obase = 0;
    for (int i = 0; i < b; ++i) { cbase += lens[i]; obase += lens[i] + 1; }
    const int* cnt = cnts + cbase;
    int* off = offs + obase;
    const int len = lens[b];
    const int t = threadIdx.x, lane = t & 63, w = t >> 6;
    __shared__ int wsum[2][4];
    int carry = 0, buf = 0;
    for (int base = 0; base < len; base += 1024, buf ^= 1) {
        int i0 = base + t * 4;
        int v0 = (i0 + 0 < len) ? cnt[i0 + 0] : 0;
        int v1 = (i0 + 1 < len) ? cnt[i0 + 1] : 0;
        int v2 = (i0 + 2 < len) ? cnt[i0 + 2] : 0;
        int v3 = (i0 + 3 < len) ? cnt[i0 + 3] : 0;
        int s = v0 + v1 + v2 + v3;
        int incl = s;
#pragma unroll
        for (int d = 1; d < 64; d <<= 1) {
            int x = __shfl_up(incl, d, 64);
            if (lane >= d) incl += x;
        }
        if (lane == 63) wsum[buf][w] = incl;
        __syncthreads();
        int prefix = carry;
        for (int ww = 0; ww < w; ++ww) prefix += wsum[buf][ww];
        int excl = prefix + incl - s;
        if (i0 + 0 < len) off[i0 + 0] = excl;
        if (i0 + 1 < len) off[i0 + 1] = excl + v0;
        if (i0 + 2 < len) off[i0 + 2] = excl + v0 + v1;
        if (i0 + 3 < len) off[i0 + 3] = excl + v0 + v1 + v2;
        carry += wsum[buf][0] + wsum[buf][1] + wsum[buf][2] + wsum[buf][3];
    }
    if (t == 0) off[len] = carry;
}

// --------------------------------------------------- CSR build: fill (x6)
__global__ __launch_bounds__(256) void fill6_kernel(
    const int* e0, const int* e1, const int* e2,
    const int* n0, const int* n1, const int* n2,
    int* cntbase, const int* offbase, int* listbase)
{
    int b = blockIdx.y;
    const int* idx   = (b == 0) ? e0 : (b == 1) ? e1 : (b == 2) ? e2
                     : (b == 3) ? n0 : (b == 4) ? n1 : n2;
    const int* other = (b == 0) ? n0 : (b == 1) ? n1 : (b == 2) ? n2
                     : (b == 3) ? e0 : (b == 4) ? e1 : e2;
    int cb = (b < 3) ? b * M_EDGES : 3 * M_EDGES + (b - 3) * N_NODES;
    int ob = (b < 3) ? b * (M_EDGES + 1) : 3 * (M_EDGES + 1) + (b - 3) * (N_NODES + 1);
    int* cnt = cntbase + cb;
    const int* off = offbase + ob;
    int* list = listbase + (size_t)b * E_INC;
    int i = blockIdx.x * 256 + threadIdx.x;
    if (i >= E_INC) return;
    int e = idx[i];
    int pos = atomicSub(&cnt[e], 1) - 1;
    list[off[e] + pos] = other[i];
}

// ------------------- ebuf[e,:] = mean of xt rows (bf16), grid (2500, 3)
__global__ __launch_bounds__(256) void gedge_kernel(
    const unsigned short* __restrict__ xt,
    const int* __restrict__ listbase, const int* __restrict__ offbase,
    unsigned short* __restrict__ eb)
{
    int mm = blockIdx.y;
    const unsigned short* X = xt + (size_t)mm * N_NODES * 128;
    const int* list = listbase + (size_t)mm * E_INC;
    const int* off = offbase + mm * (M_EDGES + 1);
    unsigned short* E = eb + (size_t)mm * M_EDGES * 128;
    int t = blockIdx.x * 256 + threadIdx.x;
    int e = t >> 5, lane = t & 31;
    if (e >= M_EDGES) return;
    int s = off[e], en = off[e + 1];
    float a0 = 0, a1 = 0, a2 = 0, a3 = 0;
    for (int j = s; j < en; ++j) {
        int n = list[j];
        uint2 v = *(const uint2*)(X + (size_t)n * 128 + lane * 4);
        a0 += __uint_as_float(v.x << 16);
        a1 += __uint_as_float(v.x & 0xFFFF0000u);
        a2 += __uint_as_float(v.y << 16);
        a3 += __uint_as_float(v.y & 0xFFFF0000u);
    }
    float bi = (en > s) ? 1.f / (float)(en - s) : 0.f;
    uint2 o;
    o.x = bfb(a0 * bi) | (bfb(a1 * bi) << 16);
    o.y = bfb(a2 * bi) | (bfb(a3 * bi) << 16);
    *(uint2*)(E + (size_t)e * 128 + lane * 4) = o;
}

// ------------ rel[n,:] = mean of ebuf rows + bias (bf16), grid (6250, 3)
__global__ __launch_bounds__(256) void gnode_kernel(
    const unsigned short* __restrict__ eb,
    const int* __restrict__ listbase, const int* __restrict__ offbase,
    const float* __restrict__ b0, const float* __restrict__ b1,
    const float* __restrict__ b2, unsigned short* __restrict__ rel)
{
    int mm = blockIdx.y;
    const unsigned short* E = eb + (size_t)mm * M_EDGES * 128;
    const int* list = listbase + (size_t)(3 + mm) * E_INC;
    const int* off = offbase + 3 * (M_EDGES + 1) + mm * (N_NODES + 1);
    const float* bias = (mm == 0) ? b0 : (mm == 1) ? b1 : b2;
    unsigned short* R = rel + (size_t)mm * N_NODES * 128;
    int t = blockIdx.x * 256 + threadIdx.x;
    int n = t >> 5, lane = t & 31;
    if (n >= N_NODES) return;
    int s = off[n], en = off[n + 1];
    float a0 = 0, a1 = 0, a2 = 0, a3 = 0;
    for (int j = s; j < en; ++j) {
        int e = list[j];
        uint2 v = *(const uint2*)(E + (size_t)e * 128 + lane * 4);
        a0 += __uint_as_float(v.x << 16);
        a1 += __uint_as_float(v.x & 0xFFFF0000u);
        a2 += __uint_as_float(v.y << 16);
        a3 += __uint_as_float(v.y & 0xFFFF0000u);
    }
    float di = (en > s) ? 1.f / (float)(en - s) : 0.f;
    uint2 o;
    o.x = bfb(a0 * di + bias[lane * 4 + 0]) | (bfb(a1 * di + bias[lane * 4 + 1]) << 16);
    o.y = bfb(a2 * di + bias[lane * 4 + 2]) | (bfb(a3 * di + bias[lane * 4 + 3]) << 16);
    *(uint2*)(R + (size_t)n * 128 + lane * 4) = o;
}

// ------------------------------- fused attention: grid (128 strips, 4 pairs)
// GEMM1: S = rel @ qk^T (+cb), p = exp(S); GEMM2: PR += P^T @ rel; l = colsums
__global__ __launch_bounds__(256) void attn_kernel(
    const unsigned short* __restrict__ rel, const unsigned short* __restrict__ qkb,
    const float* __restrict__ cb, float* __restrict__ PRpart, float* __restrict__ lpart)
{
    __shared__ __align__(16) unsigned short relT[128 * 72];
    __shared__ __align__(16) unsigned short Pl[128 * 72];

    const int strip = blockIdx.x, pair = blockIdx.y;
    const int t = threadIdx.x, w = t >> 6, lane = t & 63;
    const int ln15 = lane & 15, l16 = lane >> 4;

    bf8v bq[2][4];
#pragma unroll
    for (int nt = 0; nt < 2; ++nt)
#pragma unroll
        for (int ks = 0; ks < 4; ++ks)
            bq[nt][ks] = *(const bf8v*)(qkb +
                (size_t)(pair * 128 + w * 32 + nt * 16 + ln15) * 128 + ks * 32 + l16 * 8);
    float cbr[2];
#pragma unroll
    for (int nt = 0; nt < 2; ++nt)
        cbr[nt] = cb[pair * 128 + w * 32 + nt * 16 + ln15];

    f4v pr[2][8];
#pragma unroll
    for (int i = 0; i < 2; ++i)
#pragma unroll
        for (int j = 0; j < 8; ++j) pr[i][j] = (f4v)0.f;
    float lacc[2] = {0.f, 0.f};

    const int r0s = strip * SROWS;
    const int rend = (r0s + SROWS < R_REL) ? (r0s + SROWS) : R_REL;

    for (int cidx = 0; cidx < SCHUNKS; ++cidx) {
        const int base = r0s + cidx * 64;
        if (base >= rend) break;
        const int nvalid = rend - base;
        __syncthreads();
        // ---- stage relT[j][r] (transposed, padded stride 72) ----
        uint* RT = (uint*)relT;
#pragma unroll
        for (int a = 0; a < 2; ++a) {
            int idx = t + a * 256;
            int rp = idx & 31, jg = idx >> 5;   // r-pair, j-group
            const unsigned short* p0 = rel + (size_t)(base + rp * 2) * 128 + jg * 8;
            uint4 A = *(const uint4*)p0;
            uint4 B = *(const uint4*)(p0 + 128);
            unsigned aw[4] = {A.x, A.y, A.z, A.w};
            unsigned bw[4] = {B.x, B.y, B.z, B.w};
#pragma unroll
            for (int jj = 0; jj < 4; ++jj) {
                int j0 = jg * 8 + jj * 2;
                RT[(j0    ) * 36 + rp] = (aw[jj] & 0xFFFFu) | (bw[jj] << 16);
                RT[(j0 + 1) * 36 + rp] = (aw[jj] >> 16) | (bw[jj] & 0xFFFF0000u);
            }
        }
        // ---- GEMM1: S[r, hc] ----
        f4v sc[4][2];
#pragma unroll
        for (int i = 0; i < 4; ++i) { sc[i][0] = (f4v)0.f; sc[i][1] = (f4v)0.f; }
        for (int ks = 0; ks < 4; ++ks) {
            bf8v a[4];
#pragma unroll
            for (int mt = 0; mt < 4; ++mt)
                a[mt] = *(const bf8v*)(rel + (size_t)(base + mt * 16 + ln15) * 128 + ks * 32 + l16 * 8);
#pragma unroll
            for (int mt = 0; mt < 4; ++mt) {
                sc[mt][0] = MFMA16(a[mt], bq[0][ks], sc[mt][0]);
                sc[mt][1] = MFMA16(a[mt], bq[1][ks], sc[mt][1]);
            }
        }
        // ---- exp + mask + Pl + l ----
        bool full = (nvalid >= 64);
#pragma unroll
        for (int nt = 0; nt < 2; ++nt) {
            float ls = 0.f;
#pragma unroll
            for (int mt = 0; mt < 4; ++mt) {
#pragma unroll
                for (int reg = 0; reg < 4; ++reg) {
                    int rl = mt * 16 + l16 * 4 + reg;
                    float p = __expf(sc[mt][nt][reg] + cbr[nt]);
                    if (!full && rl >= nvalid) p = 0.f;
                    ls += p;
                    Pl[(w * 32 + nt * 16 + ln15) * 72 + rl] = (unsigned short)bfb(p);
                }
            }
            ls += __shfl_xor(ls, 16, 64);
            ls += __shfl_xor(ls, 32, 64);
            lacc[nt] += ls;
        }
        __syncthreads();
        // ---- GEMM2: PR[hc, j] += P^T @ rel ----
        for (int ks = 0; ks < 2; ++ks) {
            bf8v ap[2];
#pragma unroll
            for (int mt = 0; mt < 2; ++mt)
                ap[mt] = *(const bf8v*)(Pl + (w * 32 + mt * 16 + ln15) * 72 + ks * 32 + l16 * 8);
#pragma unroll
            for (int nt = 0; nt < 8; ++nt) {
                bf8v b = *(const bf8v*)(relT + (nt * 16 + ln15) * 72 + ks * 32 + l16 * 8);
                pr[0][nt] = MFMA16(ap[0], b, pr[0][nt]);
                pr[1][nt] = MFMA16(ap[1], b, pr[1][nt]);
            }
        }
    }
    // ---- write partials ----
    float* PB = PRpart + (size_t)(pair * STRIPS + strip) * 128 * 128;
#pragma unroll
    for (int mt = 0; mt < 2; ++mt)
#pragma unroll
        for (int reg = 0; reg < 4; ++reg) {
            int hcl = w * 32 + mt * 16 + l16 * 4 + reg;
#pragma unroll
            for (int nt = 0; nt < 8; ++nt)
                PB[hcl * 128 + nt * 16 + ln15] = pr[mt][nt][reg];
        }
    if (lane < 16) {
        float* LB = lpart + (size_t)(pair * STRIPS + strip) * 128;
        LB[w * 32 + ln15] = lacc[0];
        LB[w * 32 + 16 + ln15] = lacc[1];
    }
}

// ---------------- reduce: PRsum -> o_norm -> osum (atomic), grid 512
__global__ __launch_bounds__(256) void reduce_kernel(
    const float* __restrict__ PRpart, const float* __restrict__ lpart,
    const float* __restrict__ wv, const float* __restrict__ bv,
    float* __restrict__ osum)
{
    int hc = blockIdx.x;
    int pair = hc >> 7, hcl = hc & 127, h = hc >> 6;
    __shared__ float PS[128];
    __shared__ float LL[129];
    int t = threadIdx.x;
    if (t < 128) {
        float s = 0.f;
        const float* p = PRpart + ((size_t)(pair * STRIPS) * 128 + hcl) * 128 + t;
        for (int st = 0; st < STRIPS; ++st) s += p[(size_t)st * 128 * 128];
        PS[t] = s;
    } else {
        int st = t - 128;
        LL[st] = lpart[(size_t)(pair * STRIPS + st) * 128 + hcl];
    }
    __syncthreads();
    if (t == 0) {
        float l = 0.f;
        for (int st = 0; st < 128; ++st) l += LL[st];
        LL[128] = l;
    }
    __syncthreads();
    if (t < 16) {
        float o = 0.f;
        for (int j = 0; j < 128; ++j) o += PS[j] * wv[(size_t)j * 128 + h * 16 + t];
        float on = o / LL[128] + bv[h * 16 + t];
        atomicAdd(&osum[h * 16 + t], on);
    }
}

// --- u[d] = (sum_c ctx[c,d] + (osum@wo)[d]/64 + bo[d]) / 65
__global__ __launch_bounds__(128) void user_kernel(
    const float* __restrict__ ctx, const float* __restrict__ osum,
    const float* __restrict__ wo, const float* __restrict__ bo,
    float* __restrict__ u)
{
    __shared__ float os[128];
    int d = threadIdx.x;
    os[d] = osum[d];
    __syncthreads();
    float cs = 0.f;
    for (int cc = 0; cc < 64; ++cc) cs += ctx[cc * 128 + d];
    float ow = 0.f;
    for (int j = 0; j < 128; ++j) ow += os[j] * wo[j * 128 + d];
    u[d] = (cs + ow * (1.f / 64.f) + bo[d]) * (1.f / 65.f);
}

// --------------------------------- out[j] = u @ w_rec[:,j] + b_rec[j]
__global__ __launch_bounds__(256) void rec_kernel(
    const float* __restrict__ u, const float* __restrict__ wrec,
    const float* __restrict__ brec, float* __restrict__ out)
{
    __shared__ float ul[128];
    if (threadIdx.x < 128) ul[threadIdx.x] = u[threadIdx.x];
    __syncthreads();
    int j = blockIdx.x * 256 + threadIdx.x;
    if (j >= NE_OUT) return;
    float a0 = brec[j], a1 = 0.f, a2 = 0.f, a3 = 0.f;
#pragma unroll 4
    for (int d = 0; d < 128; d += 4) {
        a0 += ul[d + 0] * wrec[(size_t)(d + 0) * NE_OUT + j];
        a1 += ul[d + 1] * wrec[(size_t)(d + 1) * NE_OUT + j];
        a2 += ul[d + 2] * wrec[(size_t)(d + 2) * NE_OUT + j];
        a3 += ul[d + 3] * wrec[(size_t)(d + 3) * NE_OUT + j];
    }
    out[j] = (a0 + a1) + (a2 + a3);
}

extern "C" void kernel_launch(void* const* d_in, const int* in_sizes, int n_in,
                              void* d_out, int out_size, void* d_ws, size_t ws_size,
                              hipStream_t stream)
{
    const float* ctx  = (const float*)d_in[9];
    const float* wq = (const float*)d_in[10];
    const float* bq = (const float*)d_in[11];
    const float* wk = (const float*)d_in[12];
    const float* bk = (const float*)d_in[13];
    const float* wv = (const float*)d_in[14];
    const float* bv = (const float*)d_in[15];
    const float* wo = (const float*)d_in[16];
    const float* bo = (const float*)d_in[17];
    const float* wrec = (const float*)d_in[18];
    const float* brec = (const float*)d_in[19];
    const int* node0 = (const int*)d_in[20];
    const int* edge0 = (const int*)d_in[21];
    const int* node1 = (const int*)d_in[22];
    const int* edge1 = (const int*)d_in[23];
    const int* node2 = (const int*)d_in[24];
    const int* edge2 = (const int*)d_in[25];
    float* out = (float*)d_out;

    char* ws = (char*)d_ws;
    size_t off = 0;
    auto alloc = [&](size_t nbytes) {
        void* p = ws + off;
        off += (nbytes + 255) & ~(size_t)255;
        return p;
    };
    unsigned short* rel  = (unsigned short*)alloc((size_t)R_REL * 128 * 2);
    unsigned short* xt   = (unsigned short*)alloc((size_t)3 * N_NODES * 128 * 2);
    unsigned short* eb   = (unsigned short*)alloc((size_t)3 * M_EDGES * 128 * 2);
    float* PRpart = (float*)alloc((size_t)4 * STRIPS * 128 * 128 * 4);
    float* lpart  = (float*)alloc((size_t)4 * STRIPS * 128 * 4);
    float* qbuf   = (float*)alloc(64 * 128 * 4);
    unsigned short* qkb = (unsigned short*)alloc(512 * 128 * 2);
    float* cbv    = (float*)alloc(512 * 4);
    unsigned short* thT = (unsigned short*)alloc(3 * 16384 * 2);
    int* cntbase  = (int*)alloc((size_t)(3 * M_EDGES + 3 * N_NODES + 128) * 4); // + osum
    float* osum   = (float*)(cntbase + 3 * M_EDGES + 3 * N_NODES);
    int* offbase  = (int*)alloc((size_t)(3 * (M_EDGES + 1) + 3 * (N_NODES + 1)) * 4);
    int* listbase = (int*)alloc((size_t)6 * E_INC * 4);
    float* u      = (float*)alloc(128 * 4);
    (void)ws_size; (void)in_sizes; (void)n_in; (void)out_size;

    // 1. zero cnt + osum (contiguous)
    {
        int nwords = 3 * M_EDGES + 3 * N_NODES + 128;   // 210128, /4 = 52532
        zero_kernel<<<(nwords / 4 + 255) / 256, 256, 0, stream>>>((float4*)cntbase, nwords / 4);
    }
    // 2-4. CSR build
    const int gE = (E_INC + 255) / 256;
    count6_kernel<<<dim3(gE, 6), 256, 0, stream>>>(edge0, edge1, edge2, node0, node1, node2, cntbase);
    scan6_kernel<<<6, 256, 0, stream>>>(cntbase, offbase);
    fill6_kernel<<<dim3(gE, 6), 256, 0, stream>>>(edge0, edge1, edge2, node0, node1, node2,
                                                  cntbase, offbase, listbase);
    // 5. weight conversion (theta^T bf16)
    wconv_kernel<<<192, 256, 0, stream>>>((const float*)d_in[1], (const float*)d_in[4],
                                          (const float*)d_in[7], thT);
    // 6-7. q projection + qk/cb precompute
    gemm128_kernel<<<2, 256, 0, stream>>>(ctx, wq, bq, qbuf, C_CTX);
    qk_kernel<<<256, 256, 0, stream>>>(qbuf, wk, bk, qkb, cbv);
    // 8. xt = x @ theta (bf16 MFMA), all modalities
    xg_kernel<<<dim3((N_NODES + 127) / 128, 3), 256, 0, stream>>>(
        (const float*)d_in[0], (const float*)d_in[3], (const float*)d_in[6], thT, xt, N_NODES);
    // 9-10. gathers
    gedge_kernel<<<dim3(M_EDGES * 32 / 256, 3), 256, 0, stream>>>(xt, listbase, offbase, eb);
    gnode_kernel<<<dim3(N_NODES * 32 / 256, 3), 256, 0, stream>>>(
        eb, listbase, offbase, (const float*)d_in[2], (const float*)d_in[5],
        (const float*)d_in[8], rel);
    // 11-12. fused attention + reduce
    attn_kernel<<<dim3(STRIPS, 4), 256, 0, stream>>>(rel, qkb, cbv, PRpart, lpart);
    reduce_kernel<<<512, 256, 0, stream>>>(PRpart, lpart, wv, bv, osum);
    // 13-14. user repr + final scores
    user_kernel<<<1, 128, 0, stream>>>(ctx, osum, wo, bo, u);
    rec_kernel<<<(NE_OUT + 255) / 256, 256, 0, stream>>>(u, wrec, brec, out);
}

// Round 4
// 645.655 us; speedup vs baseline: 5.0440x; 1.0529x over previous
//
#include <hip/hip_runtime.h>
#include <hip/hip_bf16.h>

// Problem constants (fixed by the reference setup_inputs)
constexpr int N_NODES = 50000;
constexpr int M_EDGES = 20000;
constexpr int E_INC   = 200000;
constexpr int H_HEADS = 8;
constexpr int C_CTX   = 64;
constexpr int NE_OUT  = 200000;
constexpr int R_REL   = 3 * N_NODES; // 150000

constexpr int STRIPS  = 256;         // 256x4 = 1024 blocks = 4 blocks/CU
constexpr int SROWS   = 586;         // ceil(150000/256)
constexpr int SCHUNKS = 10;          // ceil(586/64)

typedef short bf8v __attribute__((ext_vector_type(8)));   // 8 bf16 (4 VGPRs)
typedef float f4v  __attribute__((ext_vector_type(4)));   // 4 fp32 acc
#define MFMA16(a, b, c) __builtin_amdgcn_mfma_f32_16x16x32_bf16(a, b, c, 0, 0, 0)

// fp32 -> bf16 (RNE) scalar; compiler emits v_cvt equivalents
__device__ __forceinline__ unsigned short bfs(float f) {
    union { __hip_bfloat16 b; unsigned short s; } u;
    u.b = __float2bfloat16(f);
    return u.s;
}
// packed pair: low short = lo, high short = hi (v_cvt_pk_bf16_f32)
__device__ __forceinline__ unsigned bfp(float lo, float hi) {
    union { __hip_bfloat162 b; unsigned u; } v;
    v.b = __float22bfloat162_rn(make_float2(lo, hi));
    return v.u;
}

// ---------------------------------------------------------------- zero fill
__global__ __launch_bounds__(256) void zero_kernel(float4* p, int n4) {
    int i = blockIdx.x * 256 + threadIdx.x;
    if (i < n4) p[i] = make_float4(0.f, 0.f, 0.f, 0.f);
}

// ------------------------------------------- theta -> bf16 transposed [n][k]
__global__ __launch_bounds__(256) void wconv_kernel(
    const float* __restrict__ t0, const float* __restrict__ t1,
    const float* __restrict__ t2, unsigned short* __restrict__ out)
{
    int idx = blockIdx.x * 256 + threadIdx.x;   // 0..49151
    int m = idx >> 14, p = idx & 16383;
    int n = p >> 7, k = p & 127;
    const float* src = (m == 0) ? t0 : (m == 1) ? t1 : t2;
    out[idx] = bfs(src[k * 128 + n]);
}

// ---- fused q-projection + qk/cb precompute. grid 64 (one block per c).
// qk[hc][j] = 0.25 * sum_d q[c,h16+d]*wk[j,h16+d];  cb[hc] = 0.25*q.bk
__global__ __launch_bounds__(256) void qkf_kernel(
    const float* __restrict__ ctx, const float* __restrict__ wq,
    const float* __restrict__ bq, const float* __restrict__ wk,
    const float* __restrict__ bk, unsigned short* __restrict__ qkb,
    float* __restrict__ cb)
{
    __shared__ float qrow[128];
    const int c = blockIdx.x, t = threadIdx.x;
    if (t < 128) {
        float s = bq[t];
        for (int k = 0; k < 128; ++k) s += ctx[c * 128 + k] * wq[(size_t)k * 128 + t];
        qrow[t] = s;
    }
    __syncthreads();
#pragma unroll
    for (int i = 0; i < 4; ++i) {
        int idx = t + i * 256;          // 0..1023
        int h = idx >> 7, j = idx & 127;
        const float* wr = wk + (size_t)j * 128 + h * 16;
        const float* qr = qrow + h * 16;
        float s = 0.f;
#pragma unroll
        for (int d = 0; d < 16; ++d) s += qr[d] * wr[d];
        qkb[(size_t)(h * 64 + c) * 128 + j] = bfs(0.25f * s);
    }
    if (t < 8) {
        float s = 0.f;
#pragma unroll
        for (int d = 0; d < 16; ++d) s += qrow[t * 16 + d] * bk[t * 16 + d];
        cb[t * 64 + c] = 0.25f * s;
    }
}

// ------------------- xt(bf16) = x(fp32) @ theta  via MFMA, grid (391, 3)
__global__ __launch_bounds__(256) void xg_kernel(
    const float* __restrict__ x0, const float* __restrict__ x1,
    const float* __restrict__ x2, const unsigned short* __restrict__ thT,
    unsigned short* __restrict__ y, int R)
{
    int m = blockIdx.y;
    const float* X = (m == 0) ? x0 : (m == 1) ? x1 : x2;
    const unsigned short* W = thT + m * 16384;
    unsigned short* Y = y + (size_t)m * R * 128;
    const int w = threadIdx.x >> 6, lane = threadIdx.x & 63;
    const int ln15 = lane & 15, l16 = lane >> 4;
    const int r0 = blockIdx.x * 128 + w * 32;

    f4v acc[2][8];
#pragma unroll
    for (int i = 0; i < 2; ++i)
#pragma unroll
        for (int j = 0; j < 8; ++j) acc[i][j] = (f4v)0.f;

    for (int ks = 0; ks < 4; ++ks) {
        bf8v a[2];
#pragma unroll
        for (int mt = 0; mt < 2; ++mt) {
            int row = r0 + mt * 16 + ln15;
            row = (row < R) ? row : (R - 1);
            const float* xp = X + (size_t)row * 128 + ks * 32 + l16 * 8;
            float4 f0 = *(const float4*)xp;
            float4 f1 = *(const float4*)(xp + 4);
            union { bf8v v; unsigned w[4]; } u;
            u.w[0] = bfp(f0.x, f0.y);
            u.w[1] = bfp(f0.z, f0.w);
            u.w[2] = bfp(f1.x, f1.y);
            u.w[3] = bfp(f1.z, f1.w);
            a[mt] = u.v;
        }
#pragma unroll
        for (int nt = 0; nt < 8; ++nt) {
            bf8v b = *(const bf8v*)(W + (nt * 16 + ln15) * 128 + ks * 32 + l16 * 8);
            acc[0][nt] = MFMA16(a[0], b, acc[0][nt]);
            acc[1][nt] = MFMA16(a[1], b, acc[1][nt]);
        }
    }
#pragma unroll
    for (int mt = 0; mt < 2; ++mt)
#pragma unroll
        for (int reg = 0; reg < 4; ++reg) {
            int row = r0 + mt * 16 + l16 * 4 + reg;
            if (row < R) {
#pragma unroll
                for (int nt = 0; nt < 8; ++nt)
                    Y[(size_t)row * 128 + nt * 16 + ln15] = bfs(acc[mt][nt][reg]);
            }
        }
}

// --------------------------------------------------- CSR build: count (x6)
__global__ __launch_bounds__(256) void count6_kernel(
    const int* e0, const int* e1, const int* e2,
    const int* n0, const int* n1, const int* n2, int* cntbase)
{
    int b = blockIdx.y;
    const int* arr = (b == 0) ? e0 : (b == 1) ? e1 : (b == 2) ? e2
                   : (b == 3) ? n0 : (b == 4) ? n1 : n2;
    int base = (b < 3) ? b * M_EDGES : 3 * M_EDGES + (b - 3) * N_NODES;
    int i = blockIdx.x * 256 + threadIdx.x;
    if (i < E_INC) atomicAdd(cntbase + base + arr[i], 1);
}

// ------------------------------------- CSR build: 6-way scan, 1024 threads
__global__ __launch_bounds__(1024) void scan6_kernel(
    const int* __restrict__ cnts, int* __restrict__ offs)
{
    const int lens[6] = {M_EDGES, M_EDGES, M_EDGES, N_NODES, N_NODES, N_NODES};
    int b = blockIdx.x;
    int cbase = 0, obase = 0;
    for (int i = 0; i < b; ++i) { cbase += lens[i]; obase += lens[i] + 1; }
    const int* cnt = cnts + cbase;
    int* off = offs + obase;
    const int len = lens[b];
    const int t = threadIdx.x, lane = t & 63, w = t >> 6;   // 16 waves
    __shared__ int wsum[2][16];
    int carry = 0, buf = 0;
    for (int base = 0; base < len; base += 4096, buf ^= 1) {
        int i0 = base + t * 4;
        int v0 = (i0 + 0 < len) ? cnt[i0 + 0] : 0;
        int v1 = (i0 + 1 < len) ? cnt[i0 + 1] : 0;
        int v2 = (i0 + 2 < len) ? cnt[i0 + 2] : 0;
        int v3 = (i0 + 3 < len) ? cnt[i0 + 3] : 0;
        int s = v0 + v1 + v2 + v3;
        int incl = s;
#pragma unroll
        for (int d = 1; d < 64; d <<= 1) {
            int x = __shfl_up(incl, d, 64);
            if (lane >= d) incl += x;
        }
        if (lane == 63) wsum[buf][w] = incl;
        __syncthreads();
        int prefix = carry;
        for (int ww = 0; ww < w; ++ww) prefix += wsum[buf][ww];
        int excl = prefix + incl - s;
        if (i0 + 0 < len) off[i0 + 0] = excl;
        if (i0 + 1 < len) off[i0 + 1] = excl + v0;
        if (i0 + 2 < len) off[i0 + 2] = excl + v0 + v1;
        if (i0 + 3 < len) off[i0 + 3] = excl + v0 + v1 + v2;
#pragma unroll
        for (int ww = 0; ww < 16; ++ww) carry += wsum[buf][ww];
    }
    if (t == 0) off[len] = carry;
}

// --------------------------------------------------- CSR build: fill (x6)
__global__ __launch_bounds__(256) void fill6_kernel(
    const int* e0, const int* e1, const int* e2,
    const int* n0, const int* n1, const int* n2,
    int* cntbase, const int* offbase, int* listbase)
{
    int b = blockIdx.y;
    const int* idx   = (b == 0) ? e0 : (b == 1) ? e1 : (b == 2) ? e2
                     : (b == 3) ? n0 : (b == 4) ? n1 : n2;
    const int* other = (b == 0) ? n0 : (b == 1) ? n1 : (b == 2) ? n2
                     : (b == 3) ? e0 : (b == 4) ? e1 : e2;
    int cb = (b < 3) ? b * M_EDGES : 3 * M_EDGES + (b - 3) * N_NODES;
    int ob = (b < 3) ? b * (M_EDGES + 1) : 3 * (M_EDGES + 1) + (b - 3) * (N_NODES + 1);
    int* cnt = cntbase + cb;
    const int* off = offbase + ob;
    int* list = listbase + (size_t)b * E_INC;
    int i = blockIdx.x * 256 + threadIdx.x;
    if (i >= E_INC) return;
    int e = idx[i];
    int pos = atomicSub(&cnt[e], 1) - 1;
    list[off[e] + pos] = other[i];
}

// ------------------- ebuf[e,:] = mean of xt rows (bf16), grid (2500, 3)
__global__ __launch_bounds__(256) void gedge_kernel(
    const unsigned short* __restrict__ xt,
    const int* __restrict__ listbase, const int* __restrict__ offbase,
    unsigned short* __restrict__ eb)
{
    int mm = blockIdx.y;
    const unsigned short* X = xt + (size_t)mm * N_NODES * 128;
    const int* list = listbase + (size_t)mm * E_INC;
    const int* off = offbase + mm * (M_EDGES + 1);
    unsigned short* E = eb + (size_t)mm * M_EDGES * 128;
    int t = blockIdx.x * 256 + threadIdx.x;
    int e = t >> 5, lane = t & 31;
    if (e >= M_EDGES) return;
    int s = off[e], en = off[e + 1];
    float a0 = 0, a1 = 0, a2 = 0, a3 = 0;
    for (int j = s; j < en; ++j) {
        int n = list[j];
        uint2 v = *(const uint2*)(X + (size_t)n * 128 + lane * 4);
        a0 += __uint_as_float(v.x << 16);
        a1 += __uint_as_float(v.x & 0xFFFF0000u);
        a2 += __uint_as_float(v.y << 16);
        a3 += __uint_as_float(v.y & 0xFFFF0000u);
    }
    float bi = (en > s) ? 1.f / (float)(en - s) : 0.f;
    uint2 o;
    o.x = bfp(a0 * bi, a1 * bi);
    o.y = bfp(a2 * bi, a3 * bi);
    *(uint2*)(E + (size_t)e * 128 + lane * 4) = o;
}

// ------------ rel[n,:] = mean of ebuf rows + bias (bf16), grid (6250, 3)
__global__ __launch_bounds__(256) void gnode_kernel(
    const unsigned short* __restrict__ eb,
    const int* __restrict__ listbase, const int* __restrict__ offbase,
    const float* __restrict__ b0, const float* __restrict__ b1,
    const float* __restrict__ b2, unsigned short* __restrict__ rel)
{
    int mm = blockIdx.y;
    const unsigned short* E = eb + (size_t)mm * M_EDGES * 128;
    const int* list = listbase + (size_t)(3 + mm) * E_INC;
    const int* off = offbase + 3 * (M_EDGES + 1) + mm * (N_NODES + 1);
    const float* bias = (mm == 0) ? b0 : (mm == 1) ? b1 : b2;
    unsigned short* R = rel + (size_t)mm * N_NODES * 128;
    int t = blockIdx.x * 256 + threadIdx.x;
    int n = t >> 5, lane = t & 31;
    if (n >= N_NODES) return;
    int s = off[n], en = off[n + 1];
    float a0 = 0, a1 = 0, a2 = 0, a3 = 0;
    for (int j = s; j < en; ++j) {
        int e = list[j];
        uint2 v = *(const uint2*)(E + (size_t)e * 128 + lane * 4);
        a0 += __uint_as_float(v.x << 16);
        a1 += __uint_as_float(v.x & 0xFFFF0000u);
        a2 += __uint_as_float(v.y << 16);
        a3 += __uint_as_float(v.y & 0xFFFF0000u);
    }
    float di = (en > s) ? 1.f / (float)(en - s) : 0.f;
    uint2 o;
    o.x = bfp(a0 * di + bias[lane * 4 + 0], a1 * di + bias[lane * 4 + 1]);
    o.y = bfp(a2 * di + bias[lane * 4 + 2], a3 * di + bias[lane * 4 + 3]);
    *(uint2*)(R + (size_t)n * 128 + lane * 4) = o;
}

// ------------------------------- fused attention: grid (256 strips, 4 pairs)
// GEMM1: S = rel @ qk^T (+cb), p = exp(S); GEMM2: PR += P^T @ rel; l = colsums
__global__ __launch_bounds__(256) void attn_kernel(
    const unsigned short* __restrict__ rel, const unsigned short* __restrict__ qkb,
    const float* __restrict__ cb, float* __restrict__ PRpart, float* __restrict__ lpart)
{
    __shared__ __align__(16) unsigned short relT[128 * 72];
    __shared__ __align__(16) unsigned short Pl[128 * 72];

    const int strip = blockIdx.x, pair = blockIdx.y;
    const int t = threadIdx.x, w = t >> 6, lane = t & 63;
    const int ln15 = lane & 15, l16 = lane >> 4;

    bf8v bq[2][4];
#pragma unroll
    for (int nt = 0; nt < 2; ++nt)
#pragma unroll
        for (int ks = 0; ks < 4; ++ks)
            bq[nt][ks] = *(const bf8v*)(qkb +
                (size_t)(pair * 128 + w * 32 + nt * 16 + ln15) * 128 + ks * 32 + l16 * 8);
    float cbr[2];
#pragma unroll
    for (int nt = 0; nt < 2; ++nt)
        cbr[nt] = cb[pair * 128 + w * 32 + nt * 16 + ln15];

    f4v pr[2][8];
#pragma unroll
    for (int i = 0; i < 2; ++i)
#pragma unroll
        for (int j = 0; j < 8; ++j) pr[i][j] = (f4v)0.f;
    float lacc[2] = {0.f, 0.f};

    const int r0s = strip * SROWS;
    const int rend = (r0s + SROWS < R_REL) ? (r0s + SROWS) : R_REL;

    for (int cidx = 0; cidx < SCHUNKS; ++cidx) {
        const int base = r0s + cidx * 64;
        if (base >= rend) break;
        const int nvalid = rend - base;
        __syncthreads();
        // ---- stage relT[j][r] (transposed, padded stride 72) ----
        uint* RT = (uint*)relT;
#pragma unroll
        for (int a = 0; a < 2; ++a) {
            int idx = t + a * 256;
            int rp = idx & 31, jg = idx >> 5;   // r-pair, j-group
            const unsigned short* p0 = rel + (size_t)(base + rp * 2) * 128 + jg * 8;
            uint4 A = *(const uint4*)p0;
            uint4 B = *(const uint4*)(p0 + 128);
            unsigned aw[4] = {A.x, A.y, A.z, A.w};
            unsigned bw[4] = {B.x, B.y, B.z, B.w};
#pragma unroll
            for (int jj = 0; jj < 4; ++jj) {
                int j0 = jg * 8 + jj * 2;
                RT[(j0    ) * 36 + rp] = (aw[jj] & 0xFFFFu) | (bw[jj] << 16);
                RT[(j0 + 1) * 36 + rp] = (aw[jj] >> 16) | (bw[jj] & 0xFFFF0000u);
            }
        }
        // ---- GEMM1: S[r, hc] ----
        f4v sc[4][2];
#pragma unroll
        for (int i = 0; i < 4; ++i) { sc[i][0] = (f4v)0.f; sc[i][1] = (f4v)0.f; }
        for (int ks = 0; ks < 4; ++ks) {
            bf8v a[4];
#pragma unroll
            for (int mt = 0; mt < 4; ++mt)
                a[mt] = *(const bf8v*)(rel + (size_t)(base + mt * 16 + ln15) * 128 + ks * 32 + l16 * 8);
#pragma unroll
            for (int mt = 0; mt < 4; ++mt) {
                sc[mt][0] = MFMA16(a[mt], bq[0][ks], sc[mt][0]);
                sc[mt][1] = MFMA16(a[mt], bq[1][ks], sc[mt][1]);
            }
        }
        // ---- exp + mask + Pl (packed bf16x2 writes) + l ----
        bool full = (nvalid >= 64);
        unsigned* PW = (unsigned*)Pl;
#pragma unroll
        for (int nt = 0; nt < 2; ++nt) {
            float ls = 0.f;
#pragma unroll
            for (int mt = 0; mt < 4; ++mt) {
                float pv[4];
#pragma unroll
                for (int reg = 0; reg < 4; ++reg) {
                    int rl = mt * 16 + l16 * 4 + reg;
                    float p = __expf(sc[mt][nt][reg] + cbr[nt]);
                    if (!full && rl >= nvalid) p = 0.f;
                    ls += p;
                    pv[reg] = p;
                }
                int base2 = ((w * 32 + nt * 16 + ln15) * 72 + mt * 16 + l16 * 4) >> 1;
                PW[base2] = bfp(pv[0], pv[1]);
                PW[base2 + 1] = bfp(pv[2], pv[3]);
            }
            ls += __shfl_xor(ls, 16, 64);
            ls += __shfl_xor(ls, 32, 64);
            lacc[nt] += ls;
        }
        __syncthreads();
        // ---- GEMM2: PR[hc, j] += P^T @ rel ----
        for (int ks = 0; ks < 2; ++ks) {
            bf8v ap[2];
#pragma unroll
            for (int mt = 0; mt < 2; ++mt)
                ap[mt] = *(const bf8v*)(Pl + (w * 32 + mt * 16 + ln15) * 72 + ks * 32 + l16 * 8);
#pragma unroll
            for (int nt = 0; nt < 8; ++nt) {
                bf8v b = *(const bf8v*)(relT + (nt * 16 + ln15) * 72 + ks * 32 + l16 * 8);
                pr[0][nt] = MFMA16(ap[0], b, pr[0][nt]);
                pr[1][nt] = MFMA16(ap[1], b, pr[1][nt]);
            }
        }
    }
    // ---- write partials ----
    float* PB = PRpart + (size_t)(pair * STRIPS + strip) * 128 * 128;
#pragma unroll
    for (int mt = 0; mt < 2; ++mt)
#pragma unroll
        for (int reg = 0; reg < 4; ++reg) {
            int hcl = w * 32 + mt * 16 + l16 * 4 + reg;
#pragma unroll
            for (int nt = 0; nt < 8; ++nt)
                PB[hcl * 128 + nt * 16 + ln15] = pr[mt][nt][reg];
        }
    if (lane < 16) {
        float* LB = lpart + (size_t)(pair * STRIPS + strip) * 128;
        LB[w * 32 + ln15] = lacc[0];
        LB[w * 32 + 16 + ln15] = lacc[1];
    }
}

// ---------------- reduce: PRsum -> o_norm -> osum (atomic), grid 512
__global__ __launch_bounds__(256) void reduce_kernel(
    const float* __restrict__ PRpart, const float* __restrict__ lpart,
    const float* __restrict__ wv, const float* __restrict__ bv,
    float* __restrict__ osum)
{
    int hc = blockIdx.x;
    int pair = hc >> 7, hcl = hc & 127, h = hc >> 6;
    __shared__ float PS[128];
    __shared__ float LL[129];
    int t = threadIdx.x;
    if (t < 128) {
        float s = 0.f;
        const float* p = PRpart + ((size_t)(pair * STRIPS) * 128 + hcl) * 128 + t;
        for (int st = 0; st < STRIPS; ++st) s += p[(size_t)st * 128 * 128];
        PS[t] = s;
    } else {
        int idx = t - 128;   // 0..127, each covers 2 strips
        LL[idx] = lpart[(size_t)(pair * STRIPS + idx) * 128 + hcl]
                + lpart[(size_t)(pair * STRIPS + idx + 128) * 128 + hcl];
    }
    __syncthreads();
    if (t == 0) {
        float l = 0.f;
        for (int st = 0; st < 128; ++st) l += LL[st];
        LL[128] = l;
    }
    __syncthreads();
    if (t < 16) {
        float o = 0.f;
        for (int j = 0; j < 128; ++j) o += PS[j] * wv[(size_t)j * 128 + h * 16 + t];
        float on = o / LL[128] + bv[h * 16 + t];
        atomicAdd(&osum[h * 16 + t], on);
    }
}

// --- u[d] = (sum_c ctx[c,d] + (osum@wo)[d]/64 + bo[d]) / 65
__global__ __launch_bounds__(128) void user_kernel(
    const float* __restrict__ ctx, const float* __restrict__ osum,
    const float* __restrict__ wo, const float* __restrict__ bo,
    float* __restrict__ u)
{
    __shared__ float os[128];
    int d = threadIdx.x;
    os[d] = osum[d];
    __syncthreads();
    float cs = 0.f;
    for (int cc = 0; cc < 64; ++cc) cs += ctx[cc * 128 + d];
    float ow = 0.f;
    for (int j = 0; j < 128; ++j) ow += os[j] * wo[j * 128 + d];
    u[d] = (cs + ow * (1.f / 64.f) + bo[d]) * (1.f / 65.f);
}

// --------------------------------- out[j] = u @ w_rec[:,j] + b_rec[j]
__global__ __launch_bounds__(256) void rec_kernel(
    const float* __restrict__ u, const float* __restrict__ wrec,
    const float* __restrict__ brec, float* __restrict__ out)
{
    __shared__ float ul[128];
    if (threadIdx.x < 128) ul[threadIdx.x] = u[threadIdx.x];
    __syncthreads();
    int j = blockIdx.x * 256 + threadIdx.x;
    if (j >= NE_OUT) return;
    float a0 = brec[j], a1 = 0.f, a2 = 0.f, a3 = 0.f;
#pragma unroll 4
    for (int d = 0; d < 128; d += 4) {
        a0 += ul[d + 0] * wrec[(size_t)(d + 0) * NE_OUT + j];
        a1 += ul[d + 1] * wrec[(size_t)(d + 1) * NE_OUT + j];
        a2 += ul[d + 2] * wrec[(size_t)(d + 2) * NE_OUT + j];
        a3 += ul[d + 3] * wrec[(size_t)(d + 3) * NE_OUT + j];
    }
    out[j] = (a0 + a1) + (a2 + a3);
}

extern "C" void kernel_launch(void* const* d_in, const int* in_sizes, int n_in,
                              void* d_out, int out_size, void* d_ws, size_t ws_size,
                              hipStream_t stream)
{
    const float* ctx  = (const float*)d_in[9];
    const float* wq = (const float*)d_in[10];
    const float* bq = (const float*)d_in[11];
    const float* wk = (const float*)d_in[12];
    const float* bk = (const float*)d_in[13];
    const float* wv = (const float*)d_in[14];
    const float* bv = (const float*)d_in[15];
    const float* wo = (const float*)d_in[16];
    const float* bo = (const float*)d_in[17];
    const float* wrec = (const float*)d_in[18];
    const float* brec = (const float*)d_in[19];
    const int* node0 = (const int*)d_in[20];
    const int* edge0 = (const int*)d_in[21];
    const int* node1 = (const int*)d_in[22];
    const int* edge1 = (const int*)d_in[23];
    const int* node2 = (const int*)d_in[24];
    const int* edge2 = (const int*)d_in[25];
    float* out = (float*)d_out;

    char* ws = (char*)d_ws;
    size_t off = 0;
    auto alloc = [&](size_t nbytes) {
        void* p = ws + off;
        off += (nbytes + 255) & ~(size_t)255;
        return p;
    };
    unsigned short* rel  = (unsigned short*)alloc((size_t)R_REL * 128 * 2);
    unsigned short* xt   = (unsigned short*)alloc((size_t)3 * N_NODES * 128 * 2);
    unsigned short* eb   = (unsigned short*)alloc((size_t)3 * M_EDGES * 128 * 2);
    float* PRpart = (float*)alloc((size_t)4 * STRIPS * 128 * 128 * 4);   // 67 MB
    float* lpart  = (float*)alloc((size_t)4 * STRIPS * 128 * 4);
    unsigned short* qkb = (unsigned short*)alloc(512 * 128 * 2);
    float* cbv    = (float*)alloc(512 * 4);
    unsigned short* thT = (unsigned short*)alloc(3 * 16384 * 2);
    int* cntbase  = (int*)alloc((size_t)(3 * M_EDGES + 3 * N_NODES + 128) * 4); // + osum
    float* osum   = (float*)(cntbase + 3 * M_EDGES + 3 * N_NODES);
    int* offbase  = (int*)alloc((size_t)(3 * (M_EDGES + 1) + 3 * (N_NODES + 1)) * 4);
    int* listbase = (int*)alloc((size_t)6 * E_INC * 4);
    float* u      = (float*)alloc(128 * 4);
    (void)ws_size; (void)in_sizes; (void)n_in; (void)out_size;

    // 1. zero cnt + osum (contiguous)
    {
        int nwords = 3 * M_EDGES + 3 * N_NODES + 128;   // 210128, /4 = 52532
        zero_kernel<<<(nwords / 4 + 255) / 256, 256, 0, stream>>>((float4*)cntbase, nwords / 4);
    }
    // 2-4. CSR build
    const int gE = (E_INC + 255) / 256;
    count6_kernel<<<dim3(gE, 6), 256, 0, stream>>>(edge0, edge1, edge2, node0, node1, node2, cntbase);
    scan6_kernel<<<6, 1024, 0, stream>>>(cntbase, offbase);
    fill6_kernel<<<dim3(gE, 6), 256, 0, stream>>>(edge0, edge1, edge2, node0, node1, node2,
                                                  cntbase, offbase, listbase);
    // 5. weight conversion (theta^T bf16)
    wconv_kernel<<<192, 256, 0, stream>>>((const float*)d_in[1], (const float*)d_in[4],
                                          (const float*)d_in[7], thT);
    // 6. fused q projection + qk/cb precompute
    qkf_kernel<<<64, 256, 0, stream>>>(ctx, wq, bq, wk, bk, qkb, cbv);
    // 7. xt = x @ theta (bf16 MFMA), all modalities
    xg_kernel<<<dim3((N_NODES + 127) / 128, 3), 256, 0, stream>>>(
        (const float*)d_in[0], (const float*)d_in[3], (const float*)d_in[6], thT, xt, N_NODES);
    // 8-9. gathers
    gedge_kernel<<<dim3(M_EDGES * 32 / 256, 3), 256, 0, stream>>>(xt, listbase, offbase, eb);
    gnode_kernel<<<dim3(N_NODES * 32 / 256, 3), 256, 0, stream>>>(
        eb, listbase, offbase, (const float*)d_in[2], (const float*)d_in[5],
        (const float*)d_in[8], rel);
    // 10-11. fused attention + reduce
    attn_kernel<<<dim3(STRIPS, 4), 256, 0, stream>>>(rel, qkb, cbv, PRpart, lpart);
    reduce_kernel<<<512, 256, 0, stream>>>(PRpart, lpart, wv, bv, osum);
    // 12-13. user repr + final scores
    user_kernel<<<1, 128, 0, stream>>>(ctx, osum, wo, bo, u);
    rec_kernel<<<(NE_OUT + 255) / 256, 256, 0, stream>>>(u, wrec, brec, out);
}